// Round 10
// baseline (631.926 us; speedup 1.0000x reference)
//
#include <hip/hip_runtime.h>

typedef unsigned short u16;
typedef unsigned int   u32;
typedef unsigned long long u64;
typedef __attribute__((ext_vector_type(8))) short bf16x8;
typedef __attribute__((ext_vector_type(8))) unsigned short u16x8;
typedef __attribute__((ext_vector_type(4))) float f32x4;

__device__ __forceinline__ float bf2f(u16 h){ u32 u = ((u32)h)<<16; return __builtin_bit_cast(float, u); }
__device__ __forceinline__ u16 f2bf(float f){
    u32 u = __builtin_bit_cast(u32, f);
    return (u16)((u + 0x7FFFu + ((u>>16)&1u)) >> 16);   // RNE
}
// exact for bf16-valued f32 (zero low mantissa): plain truncation
__device__ __forceinline__ u16 ftrunc_bf(float f){
    return (u16)(__builtin_bit_cast(u32, f) >> 16);
}

__device__ __forceinline__ void gload16(const void* g, void* l){
    __builtin_amdgcn_global_load_lds((const __attribute__((address_space(1))) void*)g,
                                     (__attribute__((address_space(3))) void*)l, 16, 0, 0);
}

// ---------------------------------------------------------------------------
// C = X[M][K] * Y[N][K]^T * scale.  128x128 tile, BK=32, 4 waves (2x2), MFMA 16x16x32.
// F32IN=1: X,Y are float32 (bf16-valued) -> reg-stage + convert to bf16 in LDS.
// F32IN=0: X,Y are bf16 (u16) -> global_load_lds staging (R7-verified path).
// OF32=1: C float32 raw. OF32=0: C bf16 (u16).
// ---------------------------------------------------------------------------
template<int F32IN, int OF32>
__global__ __launch_bounds__(256) void gemm_bt(
    const void* __restrict__ Av, const void* __restrict__ Bv, void* __restrict__ Cv,
    int K, int ldc, float scale)
{
    __shared__ u16 lA[128*32];
    __shared__ u16 lB[128*32];
    const int rowA0 = blockIdx.y * 128;
    const int rowB0 = blockIdx.x * 128;
    const int t = threadIdx.x, lane = t & 63, w = t >> 6;
    const int wr = w >> 1, wc = w & 1;

    f32x4 acc[4][4];
    #pragma unroll
    for (int i = 0; i < 4; i++)
        #pragma unroll
        for (int j = 0; j < 4; j++) acc[i][j] = (f32x4){0.f,0.f,0.f,0.f};

    const int r0 = t >> 2,         c0 = (t & 3) << 3;
    const int r1 = (t + 256) >> 2, c1 = ((t + 256) & 3) << 3;
    const int laneRow = lane & 15, laneK = (lane >> 4) << 3;

    const int nK = K >> 5;
    for (int kt = 0; kt < nK; ++kt){
        const int kk = kt << 5;
        if (F32IN){
            const float* Af = (const float*)Av;
            const float* Bf = (const float*)Bv;
            // load 8 f32 per thread per half, convert exactly to bf16, stage via ds_write
            f32x4 a00 = *(const f32x4*)&Af[(size_t)(rowA0 + r0) * K + kk + c0];
            f32x4 a01 = *(const f32x4*)&Af[(size_t)(rowA0 + r0) * K + kk + c0 + 4];
            f32x4 a10 = *(const f32x4*)&Af[(size_t)(rowA0 + r1) * K + kk + c1];
            f32x4 a11 = *(const f32x4*)&Af[(size_t)(rowA0 + r1) * K + kk + c1 + 4];
            f32x4 b00 = *(const f32x4*)&Bf[(size_t)(rowB0 + r0) * K + kk + c0];
            f32x4 b01 = *(const f32x4*)&Bf[(size_t)(rowB0 + r0) * K + kk + c0 + 4];
            f32x4 b10 = *(const f32x4*)&Bf[(size_t)(rowB0 + r1) * K + kk + c1];
            f32x4 b11 = *(const f32x4*)&Bf[(size_t)(rowB0 + r1) * K + kk + c1 + 4];
            u16x8 ua0, ua1, ub0, ub1;
            #pragma unroll
            for (int j = 0; j < 4; j++){
                ua0[j] = ftrunc_bf(a00[j]); ua0[j+4] = ftrunc_bf(a01[j]);
                ua1[j] = ftrunc_bf(a10[j]); ua1[j+4] = ftrunc_bf(a11[j]);
                ub0[j] = ftrunc_bf(b00[j]); ub0[j+4] = ftrunc_bf(b01[j]);
                ub1[j] = ftrunc_bf(b10[j]); ub1[j+4] = ftrunc_bf(b11[j]);
            }
            __syncthreads();   // previous tile's fragment reads complete
            *(u16x8*)&lA[(size_t)t * 8]         = ua0;
            *(u16x8*)&lA[(size_t)(t + 256) * 8] = ua1;
            *(u16x8*)&lB[(size_t)t * 8]         = ub0;
            *(u16x8*)&lB[(size_t)(t + 256) * 8] = ub1;
            __syncthreads();   // tile visible
        } else {
            const u16* Au = (const u16*)Av;
            const u16* Bu = (const u16*)Bv;
            gload16(Au + (size_t)(rowA0 + r0) * K + kk + c0, &lA[t * 8]);
            gload16(Bu + (size_t)(rowB0 + r0) * K + kk + c0, &lB[t * 8]);
            gload16(Au + (size_t)(rowA0 + r1) * K + kk + c1, &lA[(t + 256) * 8]);
            gload16(Bu + (size_t)(rowB0 + r1) * K + kk + c1, &lB[(t + 256) * 8]);
            __syncthreads();
        }

        bf16x8 af[4], bfv[4];
        #pragma unroll
        for (int mi = 0; mi < 4; mi++)
            af[mi] = *(const bf16x8*)&lA[(wr*64 + mi*16 + laneRow) * 32 + laneK];
        #pragma unroll
        for (int ni = 0; ni < 4; ni++)
            bfv[ni] = *(const bf16x8*)&lB[(wc*64 + ni*16 + laneRow) * 32 + laneK];

        #pragma unroll
        for (int mi = 0; mi < 4; mi++)
            #pragma unroll
            for (int ni = 0; ni < 4; ni++)
                acc[mi][ni] = __builtin_amdgcn_mfma_f32_16x16x32_bf16(af[mi], bfv[ni], acc[mi][ni], 0, 0, 0);
        if (!F32IN) __syncthreads();
    }

    // D: col = lane&15 (Y row idx), row = (lane>>4)*4 + reg (X row idx)  [m89, R6-probe-verified]
    const int rowBase = rowA0 + wr*64;
    const int colBase = rowB0 + wc*64;
    #pragma unroll
    for (int mi = 0; mi < 4; mi++){
        #pragma unroll
        for (int ni = 0; ni < 4; ni++){
            f32x4 a = acc[mi][ni];
            const int cc = colBase + ni*16 + laneRow;
            const int rr = rowBase + mi*16 + ((lane >> 4) << 2);
            #pragma unroll
            for (int r = 0; r < 4; r++){
                const size_t idx = (size_t)(rr + r) * ldc + cc;
                float v = a[r] * scale;
                if (OF32) ((float*)Cv)[idx] = v;          // raw f32 (harness bf16-casts to compare)
                else      ((u16*)Cv)[idx]  = f2bf(v);     // faithful bf16 intermediate
            }
        }
    }
}

__device__ __forceinline__ u32 shfl_u32(u32 v, int srcx){ return (u32)__shfl_xor((int)v, srcx, 64); }
__device__ __forceinline__ u64 shflxor64(u64 x, int off){
    u32 lo = (u32)x, hi = (u32)(x >> 32);
    lo = shfl_u32(lo, off); hi = shfl_u32(hi, off);
    return (((u64)hi) << 32) | lo;
}

// per row: f32 softmax over bf16 logits; bf16 probs -> pr; argmax over bf16 probs, first-tie.
// hist -> dout[4194304+row] (f32), browse -> dout[4195328].
__global__ __launch_bounds__(256) void softmax_argmax16(
    const u16* __restrict__ sc16, u16* __restrict__ probs,
    float* __restrict__ dout, const int* __restrict__ segp)
{
    const int row = blockIdx.x;
    const u16* s = sc16 + (size_t)row * 2048;
    u16* p = probs + (size_t)row * 2048;
    const int t = threadIdx.x, lane = t & 63, w = t >> 6;

    u16x8 rv = *(const u16x8*)(s + (size_t)t * 8);
    float v[8];
    #pragma unroll
    for (int j = 0; j < 8; j++) v[j] = bf2f(rv[j]);

    float mx = v[0];
    #pragma unroll
    for (int j = 1; j < 8; j++) mx = fmaxf(mx, v[j]);
    #pragma unroll
    for (int off = 32; off; off >>= 1) mx = fmaxf(mx, __shfl_xor(mx, off, 64));
    __shared__ float smax[4];
    if (lane == 0) smax[w] = mx;
    __syncthreads();
    mx = fmaxf(fmaxf(smax[0], smax[1]), fmaxf(smax[2], smax[3]));

    float e[8]; float sum = 0.f;
    #pragma unroll
    for (int j = 0; j < 8; j++){ e[j] = expf(v[j] - mx); sum += e[j]; }
    #pragma unroll
    for (int off = 32; off; off >>= 1) sum += __shfl_xor(sum, off, 64);
    __shared__ float ssum[4];
    if (lane == 0) ssum[w] = sum;
    __syncthreads();
    sum = ssum[0] + ssum[1] + ssum[2] + ssum[3];

    u16x8 pv;
    u64 best = 0ull;
    #pragma unroll
    for (int j = 0; j < 8; j++){
        u16 pb = f2bf(e[j] / sum);
        pv[j] = pb;
        u64 key = (((u64)pb) << 32) | (u32)(0x7FFFFFFF - (t*8 + j));
        if (key > best) best = key;
    }
    *(u16x8*)(p + (size_t)t * 8) = pv;

    #pragma unroll
    for (int off = 32; off; off >>= 1){
        u64 o = shflxor64(best, off);
        if (o > best) best = o;
    }
    __shared__ u64 sb[4];
    if (lane == 0) sb[w] = best;
    __syncthreads();
    if (t == 0){
        u64 bb = sb[0];
        if (sb[1] > bb) bb = sb[1];
        if (sb[2] > bb) bb = sb[2];
        if (sb[3] > bb) bb = sb[3];
        int idx = 0x7FFFFFFF - (int)(bb & 0xFFFFFFFFu);
        float hv = (float)(segp[0] - idx);
        dout[4194304 + row] = hv;
        if (row == 0) dout[4195328] = (hv < 4.0f) ? 1.0f : 0.0f;
    }
}

// memory (f32, bf16-valued) [2048][4096] -> memT (bf16) [4096][2048]
__global__ __launch_bounds__(256) void transpose_f2b(
    const float* __restrict__ in, u16* __restrict__ out)
{
    __shared__ u16 tile[64][65];
    const int c0 = blockIdx.x * 64;   // input col (d)
    const int r0 = blockIdx.y * 64;   // input row (m)
    const int x = threadIdx.x & 63, y = threadIdx.x >> 6;
    #pragma unroll
    for (int i = 0; i < 16; i++){
        int r = y + i*4;
        tile[r][x] = ftrunc_bf(in[(size_t)(r0 + r) * 4096 + c0 + x]);
    }
    __syncthreads();
    #pragma unroll
    for (int i = 0; i < 16; i++){
        int c = y + i*4;
        out[(size_t)(c0 + c) * 2048 + r0 + x] = tile[x][c];
    }
}

// ===========================================================================
extern "C" void kernel_launch(void* const* d_in, const int* in_sizes, int n_in,
                              void* d_out, int out_size, void* d_ws, size_t ws_size,
                              hipStream_t stream)
{
    // ALL tensor inputs are FLOAT32 buffers holding bf16-valued data (S8 fingerprint decode).
    const float* memory = (const float*)d_in[0];   // [2][2048][4096]
    const float* inputs = (const float*)d_in[1];   // [2][512][4096]
    const float* wq     = (const float*)d_in[2];   // [4096][4096]
    const float* wk     = (const float*)d_in[3];   // [4096][4096]
    const int*   seg    = (const int*)d_in[4];
    float* out = (float*)d_out;                    // f32: [2*512*4096][1024 hist][1 browse]

    char* ws = (char*)d_ws;
    u16* xq16 = (u16*)(ws);                 //  8 MB [1024][4096] bf16
    u16* mk16 = (u16*)(ws + (8u<<20));      // 16 MB [2048][4096] bf16 (per batch; reused for memT)
    u16* sc16 = (u16*)(ws + (24u<<20));     //  4 MB [1024][2048] bf16 logits
    u16* pr   = (u16*)(ws + (28u<<20));     //  4 MB [1024][2048] bf16 probs
    // total ws use: 32 MB (proven safe)

    dim3 blk(256);

    // 1) xq = bf16(inputs @ wq^T)   [1024 x 4096], K=4096
    gemm_bt<1,0><<<dim3(32, 8, 1), blk, 0, stream>>>(inputs, wq, xq16, 4096, 4096, 1.0f);

    // 2) per batch: mk = bf16(memory_b @ wk^T); scores_b = bf16(xq_b @ mk^T / 64)
    for (int b = 0; b < 2; ++b){
        const float* memb = memory + (size_t)b * 2048 * 4096;
        gemm_bt<1,0><<<dim3(32, 16, 1), blk, 0, stream>>>(memb, wk, mk16, 4096, 4096, 1.0f);
        gemm_bt<0,0><<<dim3(16, 4, 1), blk, 0, stream>>>(xq16 + (size_t)b*512*4096, mk16,
                                                         sc16 + (size_t)b*512*2048,
                                                         4096, 2048, 0.015625f);
    }

    // 3) softmax (f32 over bf16 logits) -> bf16 probs; argmax bf16 probs first-tie -> hist/browse
    softmax_argmax16<<<dim3(1024), blk, 0, stream>>>(sc16, pr, out, seg);

    // 4) per batch: memT = bf16(memory_b)^T into mk16 region (dead); out_b = probs_b @ memT^T (f32)
    for (int b = 0; b < 2; ++b){
        const float* memb = memory + (size_t)b * 2048 * 4096;
        transpose_f2b<<<dim3(64, 32, 1), blk, 0, stream>>>(memb, mk16);
        gemm_bt<0,1><<<dim3(32, 4, 1), blk, 0, stream>>>(pr + (size_t)b*512*2048, mk16,
                                                         out + (size_t)b*512*4096,
                                                         2048, 4096, 1.0f);
    }
}

// Round 11
// 403.780 us; speedup vs baseline: 1.5650x; 1.5650x over previous
//
#include <hip/hip_runtime.h>

typedef unsigned short u16;
typedef unsigned int   u32;
typedef unsigned long long u64;
typedef __attribute__((ext_vector_type(8))) short bf16x8;
typedef __attribute__((ext_vector_type(8))) unsigned short u16x8;
typedef __attribute__((ext_vector_type(4))) float f32x4;

__device__ __forceinline__ float bf2f(u16 h){ u32 u = ((u32)h)<<16; return __builtin_bit_cast(float, u); }
__device__ __forceinline__ u16 f2bf(float f){
    u32 u = __builtin_bit_cast(u32, f);
    return (u16)((u + 0x7FFFu + ((u>>16)&1u)) >> 16);   // RNE
}
__device__ __forceinline__ u16 ftrunc_bf(float f){      // exact for bf16-valued f32
    return (u16)(__builtin_bit_cast(u32, f) >> 16);
}

__device__ __forceinline__ void gload16(const void* g, void* l){
    __builtin_amdgcn_global_load_lds((const __attribute__((address_space(1))) void*)g,
                                     (__attribute__((address_space(3))) void*)l, 16, 0, 0);
}

// ============================ FAST-PATH KERNELS =============================

// f32 (bf16-valued) -> bf16, vectorized, grid-stride. n8 = nelems/8.
__global__ __launch_bounds__(256) void cvt_f2b(
    const float* __restrict__ in, u16* __restrict__ out, long n8)
{
    for (long i = (long)blockIdx.x * 256 + threadIdx.x; i < n8; i += (long)gridDim.x * 256){
        f32x4 a = *(const f32x4*)(in + i*8);
        f32x4 b = *(const f32x4*)(in + i*8 + 4);
        u16x8 o;
        #pragma unroll
        for (int j = 0; j < 4; j++){ o[j] = ftrunc_bf(a[j]); o[j+4] = ftrunc_bf(b[j]); }
        *(u16x8*)(out + i*8) = o;
    }
}

// bf16 GEMM body (gload_lds, 128x128, BK=32, 4 waves). C = A * B^T * scale.
// Returns via pointer params; shared by gemm_b16 and proj_fused.
template<int OF32>
__device__ __forceinline__ void gemm_body(
    const u16* __restrict__ A, const u16* __restrict__ B, void* __restrict__ Cv,
    int K, int ldc, int rowA0, int rowB0, float scale,
    u16* lA, u16* lB)
{
    const int t = threadIdx.x, lane = t & 63, w = t >> 6;
    const int wr = w >> 1, wc = w & 1;

    f32x4 acc[4][4];
    #pragma unroll
    for (int i = 0; i < 4; i++)
        #pragma unroll
        for (int j = 0; j < 4; j++) acc[i][j] = (f32x4){0.f,0.f,0.f,0.f};

    const int r0 = t >> 2,         c0 = (t & 3) << 3;
    const int r1 = (t + 256) >> 2, c1 = ((t + 256) & 3) << 3;
    const int laneRow = lane & 15, laneK = (lane >> 4) << 3;

    const int nK = K >> 5;
    for (int kt = 0; kt < nK; ++kt){
        const int kk = kt << 5;
        gload16(A + (size_t)(rowA0 + r0) * K + kk + c0, &lA[t * 8]);
        gload16(B + (size_t)(rowB0 + r0) * K + kk + c0, &lB[t * 8]);
        gload16(A + (size_t)(rowA0 + r1) * K + kk + c1, &lA[(t + 256) * 8]);
        gload16(B + (size_t)(rowB0 + r1) * K + kk + c1, &lB[(t + 256) * 8]);
        __syncthreads();

        bf16x8 af[4], bfv[4];
        #pragma unroll
        for (int mi = 0; mi < 4; mi++)
            af[mi] = *(const bf16x8*)&lA[(wr*64 + mi*16 + laneRow) * 32 + laneK];
        #pragma unroll
        for (int ni = 0; ni < 4; ni++)
            bfv[ni] = *(const bf16x8*)&lB[(wc*64 + ni*16 + laneRow) * 32 + laneK];

        #pragma unroll
        for (int mi = 0; mi < 4; mi++)
            #pragma unroll
            for (int ni = 0; ni < 4; ni++)
                acc[mi][ni] = __builtin_amdgcn_mfma_f32_16x16x32_bf16(af[mi], bfv[ni], acc[mi][ni], 0, 0, 0);
        __syncthreads();
    }

    const int rowBase = rowA0 + wr*64;
    const int colBase = rowB0 + wc*64;
    #pragma unroll
    for (int mi = 0; mi < 4; mi++){
        #pragma unroll
        for (int ni = 0; ni < 4; ni++){
            f32x4 a = acc[mi][ni];
            const int cc = colBase + ni*16 + laneRow;
            const int rr = rowBase + mi*16 + ((lane >> 4) << 2);
            #pragma unroll
            for (int r = 0; r < 4; r++){
                const size_t idx = (size_t)(rr + r) * ldc + cc;
                float v = a[r] * scale;
                if (OF32) ((float*)Cv)[idx] = v;
                else      ((u16*)Cv)[idx]  = f2bf(v);
            }
        }
    }
}

// batched bf16 GEMM: z = batch, strides in elements
template<int OF32>
__global__ __launch_bounds__(256) void gemm_b16(
    const u16* __restrict__ A, const u16* __restrict__ B, void* __restrict__ Cv,
    int K, int ldc, long aBatch, long bBatch, long cBatch, float scale)
{
    __shared__ u16 lA[128*32];
    __shared__ u16 lB[128*32];
    const int b = blockIdx.z;
    const u16* Ab = A + (size_t)b * aBatch;
    const u16* Bb = B + (size_t)b * bBatch;
    void* Cb = OF32 ? (void*)((float*)Cv + (size_t)b * cBatch)
                    : (void*)((u16*)Cv  + (size_t)b * cBatch);
    gemm_body<OF32>(Ab, Bb, Cb, K, ldc, blockIdx.y * 128, blockIdx.x * 128, scale, lA, lB);
}

// fused projections: z=0,1 -> mk_b = mem16_b @ wk16^T (2048 rows); z=2 -> xq = in16 @ wq16^T (1024 rows)
__global__ __launch_bounds__(256) void proj_fused(
    const u16* __restrict__ mem16, const u16* __restrict__ wk16, u16* __restrict__ mk16,
    const u16* __restrict__ in16,  const u16* __restrict__ wq16, u16* __restrict__ xq16)
{
    __shared__ u16 lA[128*32];
    __shared__ u16 lB[128*32];
    const int z = blockIdx.z;
    const u16 *A, *B; u16* C;
    if (z < 2){
        A = mem16 + (size_t)z * 2048 * 4096; B = wk16; C = mk16 + (size_t)z * 2048 * 4096;
    } else {
        if (blockIdx.y >= 8) return;   // xq has 1024 rows
        A = in16; B = wq16; C = xq16;
    }
    gemm_body<0>(A, B, C, 4096, 4096, blockIdx.y * 128, blockIdx.x * 128, 1.0f, lA, lB);
}

// bf16 transpose, batched: in [z][2048][4096] -> out [z][4096][2048]
__global__ __launch_bounds__(256) void transpose_u16(
    const u16* __restrict__ in, u16* __restrict__ out)
{
    __shared__ u16 tile[64][65];
    const size_t bi = (size_t)blockIdx.z * 2048 * 4096;
    const size_t bo = (size_t)blockIdx.z * 4096 * 2048;
    const int c0 = blockIdx.x * 64;
    const int r0 = blockIdx.y * 64;
    const int x = threadIdx.x & 63, y = threadIdx.x >> 6;
    #pragma unroll
    for (int i = 0; i < 16; i++){
        int r = y + i*4;
        tile[r][x] = in[bi + (size_t)(r0 + r) * 4096 + c0 + x];
    }
    __syncthreads();
    #pragma unroll
    for (int i = 0; i < 16; i++){
        int c = y + i*4;
        out[bo + (size_t)(c0 + c) * 2048 + r0 + x] = tile[x][c];
    }
}

// ===================== SHARED: softmax / argmax / hist =====================
__device__ __forceinline__ u32 shfl_u32(u32 v, int srcx){ return (u32)__shfl_xor((int)v, srcx, 64); }
__device__ __forceinline__ u64 shflxor64(u64 x, int off){
    u32 lo = (u32)x, hi = (u32)(x >> 32);
    lo = shfl_u32(lo, off); hi = shfl_u32(hi, off);
    return (((u64)hi) << 32) | lo;
}

__global__ __launch_bounds__(256) void softmax_argmax16(
    const u16* __restrict__ sc16, u16* __restrict__ probs,
    float* __restrict__ dout, const int* __restrict__ segp)
{
    const int row = blockIdx.x;
    const u16* s = sc16 + (size_t)row * 2048;
    u16* p = probs + (size_t)row * 2048;
    const int t = threadIdx.x, lane = t & 63, w = t >> 6;

    u16x8 rv = *(const u16x8*)(s + (size_t)t * 8);
    float v[8];
    #pragma unroll
    for (int j = 0; j < 8; j++) v[j] = bf2f(rv[j]);

    float mx = v[0];
    #pragma unroll
    for (int j = 1; j < 8; j++) mx = fmaxf(mx, v[j]);
    #pragma unroll
    for (int off = 32; off; off >>= 1) mx = fmaxf(mx, __shfl_xor(mx, off, 64));
    __shared__ float smax[4];
    if (lane == 0) smax[w] = mx;
    __syncthreads();
    mx = fmaxf(fmaxf(smax[0], smax[1]), fmaxf(smax[2], smax[3]));

    float e[8]; float sum = 0.f;
    #pragma unroll
    for (int j = 0; j < 8; j++){ e[j] = expf(v[j] - mx); sum += e[j]; }
    #pragma unroll
    for (int off = 32; off; off >>= 1) sum += __shfl_xor(sum, off, 64);
    __shared__ float ssum[4];
    if (lane == 0) ssum[w] = sum;
    __syncthreads();
    sum = ssum[0] + ssum[1] + ssum[2] + ssum[3];

    u16x8 pv;
    u64 best = 0ull;
    #pragma unroll
    for (int j = 0; j < 8; j++){
        u16 pb = f2bf(e[j] / sum);
        pv[j] = pb;
        u64 key = (((u64)pb) << 32) | (u32)(0x7FFFFFFF - (t*8 + j));
        if (key > best) best = key;
    }
    *(u16x8*)(p + (size_t)t * 8) = pv;

    #pragma unroll
    for (int off = 32; off; off >>= 1){
        u64 o = shflxor64(best, off);
        if (o > best) best = o;
    }
    __shared__ u64 sb[4];
    if (lane == 0) sb[w] = best;
    __syncthreads();
    if (t == 0){
        u64 bb = sb[0];
        if (sb[1] > bb) bb = sb[1];
        if (sb[2] > bb) bb = sb[2];
        if (sb[3] > bb) bb = sb[3];
        int idx = 0x7FFFFFFF - (int)(bb & 0xFFFFFFFFu);
        float hv = (float)(segp[0] - idx);
        dout[4194304 + row] = hv;
        if (row == 0) dout[4195328] = (hv < 4.0f) ? 1.0f : 0.0f;
    }
}

// ====================== FALLBACK KERNELS (R10 verbatim) =====================
template<int F32IN, int OF32>
__global__ __launch_bounds__(256) void gemm_bt(
    const void* __restrict__ Av, const void* __restrict__ Bv, void* __restrict__ Cv,
    int K, int ldc, float scale)
{
    __shared__ u16 lA[128*32];
    __shared__ u16 lB[128*32];
    const int rowA0 = blockIdx.y * 128;
    const int rowB0 = blockIdx.x * 128;
    const int t = threadIdx.x, lane = t & 63, w = t >> 6;
    const int wr = w >> 1, wc = w & 1;

    f32x4 acc[4][4];
    #pragma unroll
    for (int i = 0; i < 4; i++)
        #pragma unroll
        for (int j = 0; j < 4; j++) acc[i][j] = (f32x4){0.f,0.f,0.f,0.f};

    const int r0 = t >> 2,         c0 = (t & 3) << 3;
    const int r1 = (t + 256) >> 2, c1 = ((t + 256) & 3) << 3;
    const int laneRow = lane & 15, laneK = (lane >> 4) << 3;

    const int nK = K >> 5;
    for (int kt = 0; kt < nK; ++kt){
        const int kk = kt << 5;
        if (F32IN){
            const float* Af = (const float*)Av;
            const float* Bf = (const float*)Bv;
            f32x4 a00 = *(const f32x4*)&Af[(size_t)(rowA0 + r0) * K + kk + c0];
            f32x4 a01 = *(const f32x4*)&Af[(size_t)(rowA0 + r0) * K + kk + c0 + 4];
            f32x4 a10 = *(const f32x4*)&Af[(size_t)(rowA0 + r1) * K + kk + c1];
            f32x4 a11 = *(const f32x4*)&Af[(size_t)(rowA0 + r1) * K + kk + c1 + 4];
            f32x4 b00 = *(const f32x4*)&Bf[(size_t)(rowB0 + r0) * K + kk + c0];
            f32x4 b01 = *(const f32x4*)&Bf[(size_t)(rowB0 + r0) * K + kk + c0 + 4];
            f32x4 b10 = *(const f32x4*)&Bf[(size_t)(rowB0 + r1) * K + kk + c1];
            f32x4 b11 = *(const f32x4*)&Bf[(size_t)(rowB0 + r1) * K + kk + c1 + 4];
            u16x8 ua0, ua1, ub0, ub1;
            #pragma unroll
            for (int j = 0; j < 4; j++){
                ua0[j] = ftrunc_bf(a00[j]); ua0[j+4] = ftrunc_bf(a01[j]);
                ua1[j] = ftrunc_bf(a10[j]); ua1[j+4] = ftrunc_bf(a11[j]);
                ub0[j] = ftrunc_bf(b00[j]); ub0[j+4] = ftrunc_bf(b01[j]);
                ub1[j] = ftrunc_bf(b10[j]); ub1[j+4] = ftrunc_bf(b11[j]);
            }
            __syncthreads();
            *(u16x8*)&lA[(size_t)t * 8]         = ua0;
            *(u16x8*)&lA[(size_t)(t + 256) * 8] = ua1;
            *(u16x8*)&lB[(size_t)t * 8]         = ub0;
            *(u16x8*)&lB[(size_t)(t + 256) * 8] = ub1;
            __syncthreads();
        } else {
            const u16* Au = (const u16*)Av;
            const u16* Bu = (const u16*)Bv;
            gload16(Au + (size_t)(rowA0 + r0) * K + kk + c0, &lA[t * 8]);
            gload16(Bu + (size_t)(rowB0 + r0) * K + kk + c0, &lB[t * 8]);
            gload16(Au + (size_t)(rowA0 + r1) * K + kk + c1, &lA[(t + 256) * 8]);
            gload16(Bu + (size_t)(rowB0 + r1) * K + kk + c1, &lB[(t + 256) * 8]);
            __syncthreads();
        }

        bf16x8 af[4], bfv[4];
        #pragma unroll
        for (int mi = 0; mi < 4; mi++)
            af[mi] = *(const bf16x8*)&lA[(wr*64 + mi*16 + laneRow) * 32 + laneK];
        #pragma unroll
        for (int ni = 0; ni < 4; ni++)
            bfv[ni] = *(const bf16x8*)&lB[(wc*64 + ni*16 + laneRow) * 32 + laneK];

        #pragma unroll
        for (int mi = 0; mi < 4; mi++)
            #pragma unroll
            for (int ni = 0; ni < 4; ni++)
                acc[mi][ni] = __builtin_amdgcn_mfma_f32_16x16x32_bf16(af[mi], bfv[ni], acc[mi][ni], 0, 0, 0);
        if (!F32IN) __syncthreads();
    }

    const int rowBase = rowA0 + wr*64;
    const int colBase = rowB0 + wc*64;
    #pragma unroll
    for (int mi = 0; mi < 4; mi++){
        #pragma unroll
        for (int ni = 0; ni < 4; ni++){
            f32x4 a = acc[mi][ni];
            const int cc = colBase + ni*16 + laneRow;
            const int rr = rowBase + mi*16 + ((lane >> 4) << 2);
            #pragma unroll
            for (int r = 0; r < 4; r++){
                const size_t idx = (size_t)(rr + r) * ldc + cc;
                float v = a[r] * scale;
                if (OF32) ((float*)Cv)[idx] = v;
                else      ((u16*)Cv)[idx]  = f2bf(v);
            }
        }
    }
}

__global__ __launch_bounds__(256) void transpose_f2b(
    const float* __restrict__ in, u16* __restrict__ out)
{
    __shared__ u16 tile[64][65];
    const int c0 = blockIdx.x * 64;
    const int r0 = blockIdx.y * 64;
    const int x = threadIdx.x & 63, y = threadIdx.x >> 6;
    #pragma unroll
    for (int i = 0; i < 16; i++){
        int r = y + i*4;
        tile[r][x] = ftrunc_bf(in[(size_t)(r0 + r) * 4096 + c0 + x]);
    }
    __syncthreads();
    #pragma unroll
    for (int i = 0; i < 16; i++){
        int c = y + i*4;
        out[(size_t)(c0 + c) * 2048 + r0 + x] = tile[x][c];
    }
}

// ===========================================================================
extern "C" void kernel_launch(void* const* d_in, const int* in_sizes, int n_in,
                              void* d_out, int out_size, void* d_ws, size_t ws_size,
                              hipStream_t stream)
{
    const float* memory = (const float*)d_in[0];   // [2][2048][4096] f32 (bf16-valued)
    const float* inputs = (const float*)d_in[1];   // [2][512][4096]
    const float* wq     = (const float*)d_in[2];   // [4096][4096]
    const float* wk     = (const float*)d_in[3];   // [4096][4096]
    const int*   seg    = (const int*)d_in[4];
    float* out = (float*)d_out;

    char* ws = (char*)d_ws;
    dim3 blk(256);

    if (ws_size >= (152ull << 20)){
        // ---------------- FAST PATH: convert once, bf16 everywhere ----------------
        u16* mem16 = (u16*)(ws);                        // 33.55 MB [2][2048][4096]
        u16* in16  = (u16*)(ws + 33554432);             //  8.39 MB [1024][4096]
        u16* wq16  = (u16*)(ws + 41943040);             // 33.55 MB
        u16* wk16  = (u16*)(ws + 75497472);             // 33.55 MB
        u16* xq16  = (u16*)(ws + 109051904);            //  8.39 MB
        u16* mk16  = (u16*)(ws + 117440512);            // 33.55 MB [2][2048][4096]; memT later
        u16* sc16  = (u16*)(ws + 150994944);            //  4.19 MB
        u16* pr    = (u16*)(ws + 155189248);            //  4.19 MB
        u16* mt    = mk16;                              // [2][4096][2048] after scores

        cvt_f2b<<<dim3(2048), blk, 0, stream>>>(memory, mem16, 2097152L);
        cvt_f2b<<<dim3(1024), blk, 0, stream>>>(inputs, in16,   524288L);
        cvt_f2b<<<dim3(2048), blk, 0, stream>>>(wq,     wq16,  2097152L);
        cvt_f2b<<<dim3(2048), blk, 0, stream>>>(wk,     wk16,  2097152L);

        // mk(b0), mk(b1), xq in one dispatch: 1280 productive blocks (~5/CU)
        proj_fused<<<dim3(32, 16, 3), blk, 0, stream>>>(mem16, wk16, mk16, in16, wq16, xq16);

        // scores_b = bf16(xq_b @ mk_b^T / 64), batched
        gemm_b16<0><<<dim3(16, 4, 2), blk, 0, stream>>>(xq16, mk16, sc16, 4096, 2048,
                                                        512L*4096, 2048L*4096, 512L*2048,
                                                        0.015625f);
        softmax_argmax16<<<dim3(1024), blk, 0, stream>>>(sc16, pr, out, seg);

        // memT (batched) into dead mk16 region, then PV batched (f32 out)
        transpose_u16<<<dim3(64, 32, 2), blk, 0, stream>>>(mem16, mt);
        gemm_b16<1><<<dim3(32, 4, 2), blk, 0, stream>>>(pr, mt, out, 2048, 4096,
                                                        512L*2048, 4096L*2048, 512L*4096,
                                                        1.0f);
    } else {
        // ---------------- FALLBACK: R10 code (passing, 632 µs) ----------------
        u16* xq16 = (u16*)(ws);
        u16* mk16 = (u16*)(ws + (8u<<20));
        u16* sc16 = (u16*)(ws + (24u<<20));
        u16* pr   = (u16*)(ws + (28u<<20));

        gemm_bt<1,0><<<dim3(32, 8, 1), blk, 0, stream>>>(inputs, wq, xq16, 4096, 4096, 1.0f);
        for (int b = 0; b < 2; ++b){
            const float* memb = memory + (size_t)b * 2048 * 4096;
            gemm_bt<1,0><<<dim3(32, 16, 1), blk, 0, stream>>>(memb, wk, mk16, 4096, 4096, 1.0f);
            gemm_bt<0,0><<<dim3(16, 4, 1), blk, 0, stream>>>(xq16 + (size_t)b*512*4096, mk16,
                                                             sc16 + (size_t)b*512*2048,
                                                             4096, 2048, 0.015625f);
        }
        softmax_argmax16<<<dim3(1024), blk, 0, stream>>>(sc16, pr, out, seg);
        for (int b = 0; b < 2; ++b){
            const float* memb = memory + (size_t)b * 2048 * 4096;
            transpose_f2b<<<dim3(64, 32, 1), blk, 0, stream>>>(memb, mk16);
            gemm_bt<0,1><<<dim3(32, 4, 1), blk, 0, stream>>>(pr + (size_t)b*512*2048, mk16,
                                                             out + (size_t)b*512*4096,
                                                             2048, 4096, 1.0f);
        }
    }
}